// Round 7
// baseline (576.285 us; speedup 1.0000x reference)
//
#include <hip/hip_runtime.h>
#include <math.h>

#define MAX_SLOTS 64
#define L 4096
#define NB2 256          // blocks in fused kernel (<= 1 block/CU guaranteed co-resident)

// ws layout (bytes)
#define OFF_CNT   0
#define OFF_LIST  64          // 64 ints (ends 320)
#define OFF_BAR   384         // 4 ints
#define OFF_FSUB  512         // 2*64*66*66*4 = 2230272 (zero-padded border)
#define OFF_K5    2230784     // 2*64*64*25*4 = 1638400  [b][c][slot][25]
#define OFF_SF    3869184     // 2*64*4096*4 = 2097152   [b][slot][P]

// ---- D0: subsample + pad zero + sf zero + mask->list + barrier init ----
__global__ __launch_bounds__(256) void k_init(const float* __restrict__ in,
                                              const int* __restrict__ mask,
                                              int* __restrict__ cnt,
                                              int* __restrict__ list,
                                              int* __restrict__ bar,
                                              float* __restrict__ fsub,
                                              float* __restrict__ sf) {
    int idx = blockIdx.x * 256 + threadIdx.x;      // 524288 data cells
    int j = idx & 63;
    int i = (idx >> 6) & 63;
    int c = (idx >> 12) & 63;
    int b = idx >> 18;
    float v = in[(((b * 128 + c) * 128) + 2 * i) * 128 + 2 * j];
    fsub[(size_t)b * 278784 + c * 4356 + (i + 1) * 66 + (j + 1)] = v;
    sf[idx] = 0.f;                                 // sf is exactly 524288 floats
    if (idx < 33280) {                             // 260 pad cells x 128 planes
        int plane = idx / 260;
        int r = idx - plane * 260;
        int pb = plane >> 6, pc = plane & 63;
        int row, col;
        if (r < 66) { row = 0; col = r; }
        else if (r < 132) { row = 65; col = r - 66; }
        else { int rr = r - 132; row = (rr >> 1) + 1; col = (rr & 1) ? 65 : 0; }
        fsub[(size_t)pb * 278784 + pc * 4356 + row * 66 + col] = 0.f;
    }
    if (blockIdx.x == 0) {
        if (threadIdx.x < 4) bar[threadIdx.x] = 0;   // ws is poisoned each call
        __shared__ int lcnt;
        if (threadIdx.x == 0) lcnt = 0;
        __syncthreads();
        for (int q = threadIdx.x; q < L; q += 256) {
            int qi = q >> 6, qj = q & 63;
            bool allz = true;
            for (int dy = -1; dy <= 1; ++dy)
                for (int dx = -1; dx <= 1; ++dx) {
                    int y = qi + dy, x = qj + dx;
                    if (y >= 0 && y < 64 && x >= 0 && x < 64)
                        allz = allz && (mask[y * 64 + x] == 0);
                }
            if (allz) {
                int p = atomicAdd(&lcnt, 1);
                if (p < MAX_SLOTS) list[p] = q;
            }
        }
        __syncthreads();
        if (threadIdx.x == 0) *cnt = (lcnt < MAX_SLOTS) ? lcnt : MAX_SLOTS;
    }
}

__device__ __forceinline__ void grid_barrier(int* bar, int phase) {
    __syncthreads();
    __threadfence();     // make this block's writes visible device-wide
    if (threadIdx.x == 0) {
        __hip_atomic_fetch_add(&bar[phase], 1, __ATOMIC_ACQ_REL, __HIP_MEMORY_SCOPE_AGENT);
        while (__hip_atomic_load(&bar[phase], __ATOMIC_ACQUIRE, __HIP_MEMORY_SCOPE_AGENT) < NB2)
            __builtin_amdgcn_s_sleep(2);
    }
    __syncthreads();
    __threadfence();     // acquire side: discard stale cached lines
}

// ---- D1: {prep || border} -> bar -> conv -> bar -> softmax+aggregate+concat ----
__global__ __launch_bounds__(256, 2) void k_fused(const float* __restrict__ in,
                                                  const int* __restrict__ mask,
                                                  const int* __restrict__ cnt,
                                                  const int* __restrict__ list,
                                                  int* __restrict__ bar,
                                                  const float* __restrict__ fsub,
                                                  float* __restrict__ K5,
                                                  float* __restrict__ sf,
                                                  float* __restrict__ out) {
    __shared__ float smem[8192];     // union: prep patch9 5184 / border 833 / out pat8 8192
    __shared__ int iflags[16];
    int tid = threadIdx.x;
    int blk = blockIdx.x;
    int nact = min(*cnt, MAX_SLOTS);

    // ===== Phase A (blocks 0..127): build collapsed 5x5 kernels K5[b][c][slot][25] =====
    if (blk < 128) {
        int slot = blk & 63, b = blk >> 6;
        if (slot >= nact) {
            for (int t = tid; t < 1600; t += 256) {
                int c = t / 25, e = t - c * 25;
                K5[(((size_t)b * 64 + c) * 64 + slot) * 25 + e] = 0.f;
            }
        } else {
            float* patch9 = smem;                 // 9*576 floats
            if (tid < 9) iflags[tid] = 0;
            __syncthreads();
            int Q = list[slot];
            const float* F = fsub + (size_t)b * 278784;
            int w = tid >> 6, lane = tid & 63;
            for (int combo = w; combo < 9; combo += 4) {
                int d2 = combo / 3 - 1, d1 = combo % 3 - 1;
                int XQ = ((Q & 63) << 6) + (Q >> 6) + d2;
                if (XQ < 0 || XQ >= L) continue;
                int YQ = ((XQ & 63) << 6) + (XQ >> 6);
                int R = YQ + d1;
                if (R < 0 || R >= L) continue;
                if (lane == 0) iflags[combo] = 1;
                int ri = R >> 6, rj = R & 63;
                const float* Fp = F + ri * 66 + rj;
                float vals[9]; float ss = 0.f;
                #pragma unroll
                for (int k = 0; k < 9; ++k) {
                    int t = lane + (k << 6);
                    int c = t / 9; int tap = t - c * 9;
                    int dy = tap / 3, dx = tap - dy * 3;
                    float v = Fp[c * 4356 + dy * 66 + dx];   // data (ri+dy-1, rj+dx-1)
                    vals[k] = v; ss += v * v;
                }
                for (int o = 32; o > 0; o >>= 1) ss += __shfl_xor(ss, o);
                float inv = 1.f / fmaxf(sqrtf(ss), 1e-8f);
                float* dst = patch9 + combo * 576;
                #pragma unroll
                for (int k = 0; k < 9; ++k) dst[lane + (k << 6)] = vals[k] * inv;
            }
            __syncthreads();
            // K5[c][oy,ox] = sum_{dy,dx} patch9[(oy-dy, ox-dx)][c][dy,dx]
            for (int t = tid; t < 1600; t += 256) {
                int c = t / 25, e = t - c * 25;
                int oy = e / 5 - 2, ox = e - (e / 5) * 5 - 2;
                float s = 0.f;
                for (int dy = -1; dy <= 1; ++dy) {
                    int dd2 = oy - dy; if (dd2 < -1 || dd2 > 1) continue;
                    for (int dx = -1; dx <= 1; ++dx) {
                        int dd1 = ox - dx; if (dd1 < -1 || dd1 > 1) continue;
                        int combo = (dd2 + 1) * 3 + (dd1 + 1);
                        if (iflags[combo])
                            s += patch9[combo * 576 + c * 9 + (dy + 1) * 3 + (dx + 1)];
                    }
                }
                K5[(((size_t)b * 64 + c) * 64 + slot) * 25 + e] = s;
            }
        }
    } else {
        // ===== Phase A' (blocks 128..255): exact border-pixel scores (independent of K5) =====
        for (int bt = blk - 128; bt < 1152; bt += 128) {
            int combo = bt % 9; int rest = bt / 9;
            int slot = rest & 63, b = rest >> 6;
            int d2 = combo / 3 - 1, d1 = combo % 3 - 1;
            int ri = 0, rj = 0;
            bool valid = (slot < nact);
            if (valid) {
                int Q = list[slot];
                int XQ = ((Q & 63) << 6) + (Q >> 6) + d2;
                valid = (XQ >= 0 && XQ < L);
                if (valid) {
                    int YQ = ((XQ & 63) << 6) + (XQ >> 6);
                    int R = YQ + d1;
                    valid = (R >= 0 && R < L);
                    if (valid) { ri = R >> 6; rj = R & 63; }
                }
            }
            if (!valid) continue;                 // block-uniform
            float* patch = smem;                  // 576
            float* red = smem + 576;              // 256
            const float* F = fsub + (size_t)b * 278784;
            const float* Fp = F + ri * 66 + rj;
            __syncthreads();                      // protect smem from previous task reads
            auto ld = [&](int t) -> float {
                int c = t / 9; int tap = t - c * 9;
                int dy = tap / 3, dx = tap - dy * 3;
                return Fp[c * 4356 + dy * 66 + dx];
            };
            float v0 = ld(tid), v1 = ld(tid + 256), v2 = (tid < 64) ? ld(tid + 512) : 0.f;
            red[tid] = v0 * v0 + v1 * v1 + v2 * v2;
            __syncthreads();
            if (tid < 64) {
                float a = red[tid] + red[tid + 64] + red[tid + 128] + red[tid + 192];
                for (int o = 32; o > 0; o >>= 1) a += __shfl_xor(a, o);
                if (tid == 0) smem[832] = 1.f / fmaxf(sqrtf(a), 1e-8f);
            }
            __syncthreads();
            float inv = smem[832];
            patch[tid] = v0 * inv; patch[tid + 256] = v1 * inv;
            if (tid < 64) patch[tid + 512] = v2 * inv;
            __syncthreads();
            if (tid < 252) {
                int i, j;
                if (tid < 64)       { i = 0;  j = tid; }
                else if (tid < 128) { i = 63; j = tid - 64; }
                else if (tid < 190) { i = tid - 127; j = 0; }
                else                { i = tid - 189; j = 63; }
                int P = (i << 6) + j;
                int XP = (j << 6) + i + d2;
                if (XP >= 0 && XP < L) {
                    int YP = ((XP & 63) << 6) + (XP >> 6);
                    int Z = YP + d1;
                    if (Z >= 0 && Z < L) {
                        int pi = Z >> 6, pj = Z & 63;
                        const float* Fz = F + pi * 66 + pj;
                        float dot = 0.f;
                        #pragma unroll 4
                        for (int c = 0; c < 64; ++c) {
                            const float* Fc = Fz + c * 4356;
                            const float* pc = patch + c * 9;
                            dot += Fc[0] * pc[0]   + Fc[1] * pc[1]   + Fc[2] * pc[2];
                            dot += Fc[66] * pc[3]  + Fc[67] * pc[4]  + Fc[68] * pc[5];
                            dot += Fc[132] * pc[6] + Fc[133] * pc[7] + Fc[134] * pc[8];
                        }
                        atomicAdd(&sf[((size_t)b * 64 + slot) * 4096 + P], dot);
                    }
                }
            }
        }
    }
    grid_barrier(bar, 0);

    // ===== Phase B: interior 5x5 conv, one wave per task, grid-strided (1984 tasks) =====
    {
        int wid = blk * 4 + (tid >> 6);          // 0..1023
        int j = tid & 63;
        for (int gw = wid; gw < 1984; gw += NB2 * 4) {
            int r   = 1 + (gw % 62);             // interior rows 1..62
            int cg2 = (gw / 62) & 15;            // 16 chunks of 4 channels
            int b   = gw / 992;
            int jc = min(max(j, 1), 62);
            const float* F = fsub + (size_t)b * 278784;
            int base = (r - 1) * 66 + (jc - 1);  // data (r-2, jc-2)
            bool active = (j >= 1 && j <= 62);
            int P = (r << 6) + j;
            for (int s0 = 0; s0 < nact; s0 += 16) {
                float acc[16];
                #pragma unroll
                for (int s = 0; s < 16; ++s) acc[s] = 0.f;
                #pragma unroll
                for (int cc = 0; cc < 4; ++cc) {
                    int c = cg2 * 4 + cc;
                    const float* Fc = F + c * 4356 + base;
                    float win[25];
                    #pragma unroll
                    for (int dy = 0; dy < 5; ++dy)
                        #pragma unroll
                        for (int dx = 0; dx < 5; ++dx)
                            win[dy * 5 + dx] = Fc[dy * 66 + dx];
                    const float* kc = K5 + (((size_t)b * 64 + c) * 64 + s0) * 25;
                    #pragma unroll
                    for (int s = 0; s < 16; ++s) {
                        #pragma unroll
                        for (int k = 0; k < 25; ++k)
                            acc[s] += kc[s * 25 + k] * win[k];
                    }
                }
                if (active) {
                    int smax = min(16, nact - s0);
                    for (int s = 0; s < smax; ++s)
                        atomicAdd(&sf[((size_t)b * 64 + (s0 + s)) * 4096 + P], acc[s]);
                }
            }
        }
    }
    grid_barrier(bar, 1);

    // ===== Phase C: inline softmax + aggregation + passthrough (1024 tasks, 4/block) =====
    float* pat8 = smem;
    for (int bt = blk; bt < 1024; bt += NB2) {   // uniform 4 iterations
        int up = bt & 63, cg8 = (bt >> 6) & 7, b = bt >> 9;
        int c0 = cg8 * 8;
        const float* inb0 = in + (size_t)b * 2097152 + (size_t)c0 * 16384;
        __syncthreads();                         // protect pat8 from previous task reads
        for (int t = tid; t < nact * 128; t += 256) {
            int s = t >> 7; int rr = t & 127;
            int cc = rr >> 4; int e = rr & 15; int aa = e >> 2; int bb = e & 3;
            int q = list[s]; int qi = q >> 6, qj = q & 63;
            int row = 2 * qi - 1 + aa, col = 2 * qj - 1 + bb;
            float v = (row >= 0 && row < 128 && col >= 0 && col < 128)
                      ? inb0[(size_t)cc * 16384 + row * 128 + col] : 0.f;
            pat8[t] = v;
        }
        __syncthreads();
        int uu = tid >> 7, v = tid & 127;
        int u = up * 2 + uu;
        float y[8];
        #pragma unroll
        for (int cc = 0; cc < 8; ++cc) y[cc] = 0.f;
        if (mask[(u >> 1) * 64 + (v >> 1)] != 0 && nact > 0) {
            int pa = (u + 1) & 1, pb = (v + 1) & 1;
            int i0 = (u + 1 - pa) >> 1, j0 = (v + 1 - pb) >> 1;
            int Pp[4]; int tap[4]; bool val[4];
            #pragma unroll
            for (int di = 0; di < 2; ++di)
                #pragma unroll
                for (int dj = 0; dj < 2; ++dj) {
                    int p = di * 2 + dj;
                    int i = i0 - di, j = j0 - dj;
                    val[p] = (i >= 0 && i < 64 && j >= 0 && j < 64);
                    Pp[p] = val[p] ? ((i << 6) + j) : 0;
                    tap[p] = (pa + 2 * di) * 4 + (pb + 2 * dj);
                }
            const float* sfb = sf + (size_t)b * 64 * 4096;
            float Mx[4] = {0.f, 0.f, 0.f, 0.f};     // masked rows contribute logit 0
            for (int s = 0; s < nact; ++s) {
                const float* srow = sfb + (size_t)s * 4096;
                #pragma unroll
                for (int p = 0; p < 4; ++p)
                    if (val[p]) Mx[p] = fmaxf(Mx[p], 10.f * srow[Pp[p]]);
            }
            float den[4];
            #pragma unroll
            for (int p = 0; p < 4; ++p) den[p] = (float)(L - nact) * expf(-Mx[p]);
            for (int s = 0; s < nact; ++s) {
                const float* srow = sfb + (size_t)s * 4096;
                #pragma unroll
                for (int p = 0; p < 4; ++p)
                    if (val[p]) den[p] += expf(10.f * srow[Pp[p]] - Mx[p]);
            }
            float inv[4];
            #pragma unroll
            for (int p = 0; p < 4; ++p) inv[p] = val[p] ? 1.f / den[p] : 0.f;
            for (int s = 0; s < nact; ++s) {
                const float* srow = sfb + (size_t)s * 4096;
                const float* ps = pat8 + s * 128;
                #pragma unroll
                for (int p = 0; p < 4; ++p) {
                    if (!val[p]) continue;
                    float wv = expf(10.f * srow[Pp[p]] - Mx[p]) * inv[p];
                    #pragma unroll
                    for (int cc = 0; cc < 8; ++cc)
                        y[cc] += wv * ps[cc * 16 + tap[p]];
                }
            }
            #pragma unroll
            for (int cc = 0; cc < 8; ++cc) y[cc] *= 0.25f;
        }
        size_t ob = (size_t)(b * 192) * 16384 + (size_t)u * 128 + v;
        #pragma unroll
        for (int cc = 0; cc < 8; ++cc) {
            int c = c0 + cc;
            float pval = in[(size_t)(b * 128 + c) * 16384 + u * 128 + v];
            out[ob + (size_t)c * 16384] = pval;            // b_full
            out[ob + (size_t)(c + 64) * 16384] = pval;     // f_full
            out[ob + (size_t)(c + 128) * 16384] = y[cc];   // y
        }
    }
}

extern "C" void kernel_launch(void* const* d_in, const int* in_sizes, int n_in,
                              void* d_out, int out_size, void* d_ws, size_t ws_size,
                              hipStream_t stream) {
    const float* in = (const float*)d_in[0];
    const int* mask = (const int*)d_in[1];
    float* out = (float*)d_out;
    char* ws = (char*)d_ws;
    int* cnt    = (int*)(ws + OFF_CNT);
    int* list   = (int*)(ws + OFF_LIST);
    int* bar    = (int*)(ws + OFF_BAR);
    float* fsub = (float*)(ws + OFF_FSUB);
    float* K5   = (float*)(ws + OFF_K5);
    float* sf   = (float*)(ws + OFF_SF);

    k_init<<<2048, 256, 0, stream>>>(in, mask, cnt, list, bar, fsub, sf);
    k_fused<<<NB2, 256, 0, stream>>>(in, mask, cnt, list, bar, fsub, K5, sf, out);
}

// Round 8
// 185.913 us; speedup vs baseline: 3.0998x; 3.0998x over previous
//
#include <hip/hip_runtime.h>
#include <math.h>

#define MAX_SLOTS 64
#define L 4096

// ws layout (bytes)
#define OFF_CNT   0
#define OFF_LIST  64          // 64 ints
#define OFF_FSUB  512         // 2*64*66*66*4 = 2230272 (zero-padded border)
#define OFF_K5    2230784     // 2*64*64*25*4 = 1638400  [b][c][slot][25]
#define OFF_SF    3869184     // 2*64*4096*4 = 2097152   [b][slot][P]

// ---- D0: subsample + pad zero + sf zero + mask->list ----
__global__ __launch_bounds__(256) void k_init(const float* __restrict__ in,
                                              const int* __restrict__ mask,
                                              int* __restrict__ cnt,
                                              int* __restrict__ list,
                                              float* __restrict__ fsub,
                                              float* __restrict__ sf) {
    int idx = blockIdx.x * 256 + threadIdx.x;      // 524288 data cells
    int j = idx & 63;
    int i = (idx >> 6) & 63;
    int c = (idx >> 12) & 63;
    int b = idx >> 18;
    float v = in[(((b * 128 + c) * 128) + 2 * i) * 128 + 2 * j];
    fsub[(size_t)b * 278784 + c * 4356 + (i + 1) * 66 + (j + 1)] = v;
    sf[idx] = 0.f;                                 // sf is exactly 524288 floats
    if (idx < 33280) {                             // 260 pad cells x 128 planes
        int plane = idx / 260;
        int r = idx - plane * 260;
        int pb = plane >> 6, pc = plane & 63;
        int row, col;
        if (r < 66) { row = 0; col = r; }
        else if (r < 132) { row = 65; col = r - 66; }
        else { int rr = r - 132; row = (rr >> 1) + 1; col = (rr & 1) ? 65 : 0; }
        fsub[(size_t)pb * 278784 + pc * 4356 + row * 66 + col] = 0.f;
    }
    if (blockIdx.x == 0) {
        __shared__ int lcnt;
        if (threadIdx.x == 0) lcnt = 0;
        __syncthreads();
        for (int q = threadIdx.x; q < L; q += 256) {
            int qi = q >> 6, qj = q & 63;
            bool allz = true;
            for (int dy = -1; dy <= 1; ++dy)
                for (int dx = -1; dx <= 1; ++dx) {
                    int y = qi + dy, x = qj + dx;
                    if (y >= 0 && y < 64 && x >= 0 && x < 64)
                        allz = allz && (mask[y * 64 + x] == 0);
                }
            if (allz) {
                int p = atomicAdd(&lcnt, 1);
                if (p < MAX_SLOTS) list[p] = q;
            }
        }
        __syncthreads();
        if (threadIdx.x == 0) *cnt = (lcnt < MAX_SLOTS) ? lcnt : MAX_SLOTS;
    }
}

// ---- D1: blocks 0..127 build K5; blocks 128..1279 border pixels (one task each) ----
__global__ __launch_bounds__(256) void k_mid(const int* __restrict__ cnt,
                                             const int* __restrict__ list,
                                             const float* __restrict__ fsub,
                                             float* __restrict__ K5,
                                             float* __restrict__ sf) {
    __shared__ float smem[5184];     // prep patch9 5184 / border 833
    __shared__ int iflags[16];
    int tid = threadIdx.x;
    int blk = blockIdx.x;
    int nact = min(*cnt, MAX_SLOTS);

    if (blk < 128) {
        // ===== prep: collapsed 5x5 kernels K5[b][c][slot][25] =====
        int slot = blk & 63, b = blk >> 6;
        if (slot >= nact) {
            for (int t = tid; t < 1600; t += 256) {
                int c = t / 25, e = t - c * 25;
                K5[(((size_t)b * 64 + c) * 64 + slot) * 25 + e] = 0.f;
            }
            return;
        }
        float* patch9 = smem;                 // 9*576 floats
        if (tid < 9) iflags[tid] = 0;
        __syncthreads();
        int Q = list[slot];
        const float* F = fsub + (size_t)b * 278784;
        int w = tid >> 6, lane = tid & 63;
        for (int combo = w; combo < 9; combo += 4) {
            int d2 = combo / 3 - 1, d1 = combo % 3 - 1;
            int XQ = ((Q & 63) << 6) + (Q >> 6) + d2;
            if (XQ < 0 || XQ >= L) continue;
            int YQ = ((XQ & 63) << 6) + (XQ >> 6);
            int R = YQ + d1;
            if (R < 0 || R >= L) continue;
            if (lane == 0) iflags[combo] = 1;
            int ri = R >> 6, rj = R & 63;
            const float* Fp = F + ri * 66 + rj;
            float vals[9]; float ss = 0.f;
            #pragma unroll
            for (int k = 0; k < 9; ++k) {
                int t = lane + (k << 6);
                int c = t / 9; int tap = t - c * 9;
                int dy = tap / 3, dx = tap - dy * 3;
                float v = Fp[c * 4356 + dy * 66 + dx];   // data (ri+dy-1, rj+dx-1)
                vals[k] = v; ss += v * v;
            }
            for (int o = 32; o > 0; o >>= 1) ss += __shfl_xor(ss, o);
            float inv = 1.f / fmaxf(sqrtf(ss), 1e-8f);
            float* dst = patch9 + combo * 576;
            #pragma unroll
            for (int k = 0; k < 9; ++k) dst[lane + (k << 6)] = vals[k] * inv;
        }
        __syncthreads();
        // K5[c][oy,ox] = sum_{dy,dx} patch9[(oy-dy, ox-dx)][c][dy,dx]
        for (int t = tid; t < 1600; t += 256) {
            int c = t / 25, e = t - c * 25;
            int oy = e / 5 - 2, ox = e - (e / 5) * 5 - 2;
            float s = 0.f;
            for (int dy = -1; dy <= 1; ++dy) {
                int dd2 = oy - dy; if (dd2 < -1 || dd2 > 1) continue;
                for (int dx = -1; dx <= 1; ++dx) {
                    int dd1 = ox - dx; if (dd1 < -1 || dd1 > 1) continue;
                    int combo = (dd2 + 1) * 3 + (dd1 + 1);
                    if (iflags[combo])
                        s += patch9[combo * 576 + c * 9 + (dy + 1) * 3 + (dx + 1)];
                }
            }
            K5[(((size_t)b * 64 + c) * 64 + slot) * 25 + e] = s;
        }
        return;
    }

    // ===== border: exact per-combo scores for the 252 edge pixels =====
    int bt = blk - 128;                       // 0..1151
    int combo = bt % 9; int rest = bt / 9;
    int slot = rest & 63, b = rest >> 6;
    if (slot >= nact) return;
    int d2 = combo / 3 - 1, d1 = combo % 3 - 1;
    int Q = list[slot];
    int XQ = ((Q & 63) << 6) + (Q >> 6) + d2;
    if (XQ < 0 || XQ >= L) return;
    int YQ = ((XQ & 63) << 6) + (XQ >> 6);
    int R = YQ + d1;
    if (R < 0 || R >= L) return;
    int ri = R >> 6, rj = R & 63;
    const float* F = fsub + (size_t)b * 278784;
    float* patch = smem;                      // 576
    float* red = smem + 576;                  // 256
    const float* Fp = F + ri * 66 + rj;
    auto ld = [&](int t) -> float {
        int c = t / 9; int tap = t - c * 9;
        int dy = tap / 3, dx = tap - dy * 3;
        return Fp[c * 4356 + dy * 66 + dx];
    };
    float v0 = ld(tid), v1 = ld(tid + 256), v2 = (tid < 64) ? ld(tid + 512) : 0.f;
    red[tid] = v0 * v0 + v1 * v1 + v2 * v2;
    __syncthreads();
    if (tid < 64) {
        float a = red[tid] + red[tid + 64] + red[tid + 128] + red[tid + 192];
        for (int o = 32; o > 0; o >>= 1) a += __shfl_xor(a, o);
        if (tid == 0) smem[832] = 1.f / fmaxf(sqrtf(a), 1e-8f);
    }
    __syncthreads();
    float inv = smem[832];
    patch[tid] = v0 * inv; patch[tid + 256] = v1 * inv;
    if (tid < 64) patch[tid + 512] = v2 * inv;
    __syncthreads();
    if (tid >= 252) return;
    int i, j;
    if (tid < 64)       { i = 0;  j = tid; }
    else if (tid < 128) { i = 63; j = tid - 64; }
    else if (tid < 190) { i = tid - 127; j = 0; }
    else                { i = tid - 189; j = 63; }
    int P = (i << 6) + j;
    int XP = (j << 6) + i + d2;
    if (XP < 0 || XP >= L) return;
    int YP = ((XP & 63) << 6) + (XP >> 6);
    int Z = YP + d1;
    if (Z < 0 || Z >= L) return;
    int pi = Z >> 6, pj = Z & 63;
    const float* Fz = F + pi * 66 + pj;
    float dot = 0.f;
    #pragma unroll 4
    for (int c = 0; c < 64; ++c) {
        const float* Fc = Fz + c * 4356;
        const float* pc = patch + c * 9;
        dot += Fc[0] * pc[0]   + Fc[1] * pc[1]   + Fc[2] * pc[2];
        dot += Fc[66] * pc[3]  + Fc[67] * pc[4]  + Fc[68] * pc[5];
        dot += Fc[132] * pc[6] + Fc[133] * pc[7] + Fc[134] * pc[8];
    }
    atomicAdd(&sf[((size_t)b * 64 + slot) * 4096 + P], dot);
}

// ---- D2: interior 5x5 conv — 496 blocks x 4 waves = 1984 independent wave-tasks ----
__global__ __launch_bounds__(256) void k_conv(const float* __restrict__ fsub,
                                              const int* __restrict__ cnt,
                                              const float* __restrict__ K5,
                                              float* __restrict__ sf) {
    int nact = min(*cnt, MAX_SLOTS);
    if (nact == 0) return;
    int wid = blockIdx.x * 4 + (threadIdx.x >> 6);   // 0..1983
    int j = threadIdx.x & 63;
    int r   = 1 + (wid % 62);            // interior rows 1..62
    int cg2 = (wid / 62) & 15;           // 16 chunks of 4 channels
    int b   = wid / 992;
    int jc = min(max(j, 1), 62);
    const float* F = fsub + (size_t)b * 278784;
    int base = (r - 1) * 66 + (jc - 1);  // data (r-2, jc-2)
    bool active = (j >= 1 && j <= 62);
    int P = (r << 6) + j;
    for (int s0 = 0; s0 < nact; s0 += 16) {
        float acc[16];
        #pragma unroll
        for (int s = 0; s < 16; ++s) acc[s] = 0.f;
        #pragma unroll
        for (int cc = 0; cc < 4; ++cc) {
            int c = cg2 * 4 + cc;
            const float* Fc = F + c * 4356 + base;
            float win[25];
            #pragma unroll
            for (int dy = 0; dy < 5; ++dy)
                #pragma unroll
                for (int dx = 0; dx < 5; ++dx)
                    win[dy * 5 + dx] = Fc[dy * 66 + dx];
            const float* kc = K5 + (((size_t)b * 64 + c) * 64 + s0) * 25;
            #pragma unroll
            for (int s = 0; s < 16; ++s) {
                #pragma unroll
                for (int k = 0; k < 25; ++k)
                    acc[s] += kc[s * 25 + k] * win[k];
            }
        }
        if (active) {
            int smax = min(16, nact - s0);
            for (int s = 0; s < smax; ++s)
                atomicAdd(&sf[((size_t)b * 64 + (s0 + s)) * 4096 + P], acc[s]);
        }
    }
}

// ---- D3: inline softmax + aggregation + passthrough (1024 blocks, one task each) ----
__global__ __launch_bounds__(256) void k_tail(const float* __restrict__ in,
                                              const int* __restrict__ mask,
                                              const int* __restrict__ cnt,
                                              const int* __restrict__ list,
                                              const float* __restrict__ sf,
                                              float* __restrict__ out) {
    __shared__ float pat8[MAX_SLOTS * 128];  // [s][cc(8)][16 taps]
    int tid = threadIdx.x;
    int blk = blockIdx.x;                    // 0..1023
    int nact = min(*cnt, MAX_SLOTS);
    int up = blk & 63, cg8 = (blk >> 6) & 7, b = blk >> 9;
    int c0 = cg8 * 8;
    const float* inb0 = in + (size_t)b * 2097152 + (size_t)c0 * 16384;
    for (int t = tid; t < nact * 128; t += 256) {
        int s = t >> 7; int rr = t & 127;
        int cc = rr >> 4; int e = rr & 15; int aa = e >> 2; int bb = e & 3;
        int q = list[s]; int qi = q >> 6, qj = q & 63;
        int row = 2 * qi - 1 + aa, col = 2 * qj - 1 + bb;
        float v = (row >= 0 && row < 128 && col >= 0 && col < 128)
                  ? inb0[(size_t)cc * 16384 + row * 128 + col] : 0.f;
        pat8[t] = v;
    }
    __syncthreads();
    int uu = tid >> 7, v = tid & 127;
    int u = up * 2 + uu;
    float y[8];
    #pragma unroll
    for (int cc = 0; cc < 8; ++cc) y[cc] = 0.f;
    if (mask[(u >> 1) * 64 + (v >> 1)] != 0 && nact > 0) {
        int pa = (u + 1) & 1, pb = (v + 1) & 1;
        int i0 = (u + 1 - pa) >> 1, j0 = (v + 1 - pb) >> 1;
        int Pp[4]; int tap[4]; bool val[4];
        #pragma unroll
        for (int di = 0; di < 2; ++di)
            #pragma unroll
            for (int dj = 0; dj < 2; ++dj) {
                int p = di * 2 + dj;
                int i = i0 - di, j = j0 - dj;
                val[p] = (i >= 0 && i < 64 && j >= 0 && j < 64);
                Pp[p] = val[p] ? ((i << 6) + j) : 0;
                tap[p] = (pa + 2 * di) * 4 + (pb + 2 * dj);
            }
        const float* sfb = sf + (size_t)b * 64 * 4096;
        float Mx[4] = {0.f, 0.f, 0.f, 0.f};     // masked rows contribute logit 0
        for (int s = 0; s < nact; ++s) {
            const float* srow = sfb + (size_t)s * 4096;
            #pragma unroll
            for (int p = 0; p < 4; ++p)
                if (val[p]) Mx[p] = fmaxf(Mx[p], 10.f * srow[Pp[p]]);
        }
        float den[4];
        #pragma unroll
        for (int p = 0; p < 4; ++p) den[p] = (float)(L - nact) * expf(-Mx[p]);
        for (int s = 0; s < nact; ++s) {
            const float* srow = sfb + (size_t)s * 4096;
            #pragma unroll
            for (int p = 0; p < 4; ++p)
                if (val[p]) den[p] += expf(10.f * srow[Pp[p]] - Mx[p]);
        }
        float inv[4];
        #pragma unroll
        for (int p = 0; p < 4; ++p) inv[p] = val[p] ? 1.f / den[p] : 0.f;
        for (int s = 0; s < nact; ++s) {
            const float* srow = sfb + (size_t)s * 4096;
            const float* ps = pat8 + s * 128;
            #pragma unroll
            for (int p = 0; p < 4; ++p) {
                if (!val[p]) continue;
                float wv = expf(10.f * srow[Pp[p]] - Mx[p]) * inv[p];
                #pragma unroll
                for (int cc = 0; cc < 8; ++cc)
                    y[cc] += wv * ps[cc * 16 + tap[p]];
            }
        }
        #pragma unroll
        for (int cc = 0; cc < 8; ++cc) y[cc] *= 0.25f;
    }
    size_t ob = (size_t)(b * 192) * 16384 + (size_t)u * 128 + v;
    #pragma unroll
    for (int cc = 0; cc < 8; ++cc) {
        int c = c0 + cc;
        float pval = in[(size_t)(b * 128 + c) * 16384 + u * 128 + v];
        out[ob + (size_t)c * 16384] = pval;            // b_full
        out[ob + (size_t)(c + 64) * 16384] = pval;     // f_full
        out[ob + (size_t)(c + 128) * 16384] = y[cc];   // y
    }
}

extern "C" void kernel_launch(void* const* d_in, const int* in_sizes, int n_in,
                              void* d_out, int out_size, void* d_ws, size_t ws_size,
                              hipStream_t stream) {
    const float* in = (const float*)d_in[0];
    const int* mask = (const int*)d_in[1];
    float* out = (float*)d_out;
    char* ws = (char*)d_ws;
    int* cnt    = (int*)(ws + OFF_CNT);
    int* list   = (int*)(ws + OFF_LIST);
    float* fsub = (float*)(ws + OFF_FSUB);
    float* K5   = (float*)(ws + OFF_K5);
    float* sf   = (float*)(ws + OFF_SF);

    k_init<<<2048, 256, 0, stream>>>(in, mask, cnt, list, fsub, sf);
    k_mid<<<1280, 256, 0, stream>>>(cnt, list, fsub, K5, sf);
    k_conv<<<496, 256, 0, stream>>>(fsub, cnt, K5, sf);
    k_tail<<<1024, 256, 0, stream>>>(in, mask, cnt, list, sf, out);
}

// Round 9
// 182.759 us; speedup vs baseline: 3.1532x; 1.0173x over previous
//
#include <hip/hip_runtime.h>
#include <math.h>

#define MAX_SLOTS 64
#define L 4096

// ws layout (bytes)
#define OFF_CNT   0
#define OFF_LIST  64          // 64 ints
#define OFF_FSUB  512         // 2*64*66*66*4 = 2230272 (zero-padded border)
#define OFF_K5    2230784     // 2*64*64*28*4 = 1835008  [b][c][slot][28] (25 used, 16B-aligned rows)
#define OFF_SF    4065792     // 2*64*4096*4 = 2097152   [b][slot][P]

// ---- D0: subsample + pad zero + sf zero + mask->list ----
__global__ __launch_bounds__(256) void k_init(const float* __restrict__ in,
                                              const int* __restrict__ mask,
                                              int* __restrict__ cnt,
                                              int* __restrict__ list,
                                              float* __restrict__ fsub,
                                              float* __restrict__ sf) {
    int idx = blockIdx.x * 256 + threadIdx.x;      // 524288 data cells
    int j = idx & 63;
    int i = (idx >> 6) & 63;
    int c = (idx >> 12) & 63;
    int b = idx >> 18;
    float v = in[(((b * 128 + c) * 128) + 2 * i) * 128 + 2 * j];
    fsub[(size_t)b * 278784 + c * 4356 + (i + 1) * 66 + (j + 1)] = v;
    sf[idx] = 0.f;                                 // sf is exactly 524288 floats
    if (idx < 33280) {                             // 260 pad cells x 128 planes
        int plane = idx / 260;
        int r = idx - plane * 260;
        int pb = plane >> 6, pc = plane & 63;
        int row, col;
        if (r < 66) { row = 0; col = r; }
        else if (r < 132) { row = 65; col = r - 66; }
        else { int rr = r - 132; row = (rr >> 1) + 1; col = (rr & 1) ? 65 : 0; }
        fsub[(size_t)pb * 278784 + pc * 4356 + row * 66 + col] = 0.f;
    }
    if (blockIdx.x == 0) {
        __shared__ int lcnt;
        if (threadIdx.x == 0) lcnt = 0;
        __syncthreads();
        for (int q = threadIdx.x; q < L; q += 256) {
            int qi = q >> 6, qj = q & 63;
            bool allz = true;
            for (int dy = -1; dy <= 1; ++dy)
                for (int dx = -1; dx <= 1; ++dx) {
                    int y = qi + dy, x = qj + dx;
                    if (y >= 0 && y < 64 && x >= 0 && x < 64)
                        allz = allz && (mask[y * 64 + x] == 0);
                }
            if (allz) {
                int p = atomicAdd(&lcnt, 1);
                if (p < MAX_SLOTS) list[p] = q;
            }
        }
        __syncthreads();
        if (threadIdx.x == 0) *cnt = (lcnt < MAX_SLOTS) ? lcnt : MAX_SLOTS;
    }
}

// ---- D1: blocks 0..127 build K5; blocks 128..1279 border pixels (one task each) ----
__global__ __launch_bounds__(256) void k_mid(const int* __restrict__ cnt,
                                             const int* __restrict__ list,
                                             const float* __restrict__ fsub,
                                             float* __restrict__ K5,
                                             float* __restrict__ sf) {
    __shared__ float smem[5184];     // prep patch9 5184 / border 833
    __shared__ int iflags[16];
    int tid = threadIdx.x;
    int blk = blockIdx.x;
    int nact = min(*cnt, MAX_SLOTS);

    if (blk < 128) {
        // ===== prep: collapsed 5x5 kernels K5[b][c][slot][28] =====
        int slot = blk & 63, b = blk >> 6;
        if (slot >= nact) {
            for (int t = tid; t < 1600; t += 256) {
                int c = t / 25, e = t - c * 25;
                K5[(((size_t)b * 64 + c) * 64 + slot) * 28 + e] = 0.f;
            }
            return;
        }
        float* patch9 = smem;                 // 9*576 floats
        if (tid < 9) iflags[tid] = 0;
        __syncthreads();
        int Q = list[slot];
        const float* F = fsub + (size_t)b * 278784;
        int w = tid >> 6, lane = tid & 63;
        for (int combo = w; combo < 9; combo += 4) {
            int d2 = combo / 3 - 1, d1 = combo % 3 - 1;
            int XQ = ((Q & 63) << 6) + (Q >> 6) + d2;
            if (XQ < 0 || XQ >= L) continue;
            int YQ = ((XQ & 63) << 6) + (XQ >> 6);
            int R = YQ + d1;
            if (R < 0 || R >= L) continue;
            if (lane == 0) iflags[combo] = 1;
            int ri = R >> 6, rj = R & 63;
            const float* Fp = F + ri * 66 + rj;
            float vals[9]; float ss = 0.f;
            #pragma unroll
            for (int k = 0; k < 9; ++k) {
                int t = lane + (k << 6);
                int c = t / 9; int tap = t - c * 9;
                int dy = tap / 3, dx = tap - dy * 3;
                float v = Fp[c * 4356 + dy * 66 + dx];   // data (ri+dy-1, rj+dx-1)
                vals[k] = v; ss += v * v;
            }
            for (int o = 32; o > 0; o >>= 1) ss += __shfl_xor(ss, o);
            float inv = 1.f / fmaxf(sqrtf(ss), 1e-8f);
            float* dst = patch9 + combo * 576;
            #pragma unroll
            for (int k = 0; k < 9; ++k) dst[lane + (k << 6)] = vals[k] * inv;
        }
        __syncthreads();
        // K5[c][oy,ox] = sum_{dy,dx} patch9[(oy-dy, ox-dx)][c][dy,dx]
        for (int t = tid; t < 1600; t += 256) {
            int c = t / 25, e = t - c * 25;
            int oy = e / 5 - 2, ox = e - (e / 5) * 5 - 2;
            float s = 0.f;
            for (int dy = -1; dy <= 1; ++dy) {
                int dd2 = oy - dy; if (dd2 < -1 || dd2 > 1) continue;
                for (int dx = -1; dx <= 1; ++dx) {
                    int dd1 = ox - dx; if (dd1 < -1 || dd1 > 1) continue;
                    int combo = (dd2 + 1) * 3 + (dd1 + 1);
                    if (iflags[combo])
                        s += patch9[combo * 576 + c * 9 + (dy + 1) * 3 + (dx + 1)];
                }
            }
            K5[(((size_t)b * 64 + c) * 64 + slot) * 28 + e] = s;
        }
        return;
    }

    // ===== border: exact per-combo scores for the 252 edge pixels =====
    int bt = blk - 128;                       // 0..1151
    int combo = bt % 9; int rest = bt / 9;
    int slot = rest & 63, b = rest >> 6;
    if (slot >= nact) return;
    int d2 = combo / 3 - 1, d1 = combo % 3 - 1;
    int Q = list[slot];
    int XQ = ((Q & 63) << 6) + (Q >> 6) + d2;
    if (XQ < 0 || XQ >= L) return;
    int YQ = ((XQ & 63) << 6) + (XQ >> 6);
    int R = YQ + d1;
    if (R < 0 || R >= L) return;
    int ri = R >> 6, rj = R & 63;
    const float* F = fsub + (size_t)b * 278784;
    float* patch = smem;                      // 576
    float* red = smem + 576;                  // 256
    const float* Fp = F + ri * 66 + rj;
    auto ld = [&](int t) -> float {
        int c = t / 9; int tap = t - c * 9;
        int dy = tap / 3, dx = tap - dy * 3;
        return Fp[c * 4356 + dy * 66 + dx];
    };
    float v0 = ld(tid), v1 = ld(tid + 256), v2 = (tid < 64) ? ld(tid + 512) : 0.f;
    red[tid] = v0 * v0 + v1 * v1 + v2 * v2;
    __syncthreads();
    if (tid < 64) {
        float a = red[tid] + red[tid + 64] + red[tid + 128] + red[tid + 192];
        for (int o = 32; o > 0; o >>= 1) a += __shfl_xor(a, o);
        if (tid == 0) smem[832] = 1.f / fmaxf(sqrtf(a), 1e-8f);
    }
    __syncthreads();
    float inv = smem[832];
    patch[tid] = v0 * inv; patch[tid + 256] = v1 * inv;
    if (tid < 64) patch[tid + 512] = v2 * inv;
    __syncthreads();
    if (tid >= 252) return;
    int i, j;
    if (tid < 64)       { i = 0;  j = tid; }
    else if (tid < 128) { i = 63; j = tid - 64; }
    else if (tid < 190) { i = tid - 127; j = 0; }
    else                { i = tid - 189; j = 63; }
    int P = (i << 6) + j;
    int XP = (j << 6) + i + d2;
    if (XP < 0 || XP >= L) return;
    int YP = ((XP & 63) << 6) + (XP >> 6);
    int Z = YP + d1;
    if (Z < 0 || Z >= L) return;
    int pi = Z >> 6, pj = Z & 63;
    const float* Fz = F + pi * 66 + pj;
    float dot = 0.f;
    #pragma unroll 4
    for (int c = 0; c < 64; ++c) {
        const float* Fc = Fz + c * 4356;
        const float* pc = patch + c * 9;
        dot += Fc[0] * pc[0]   + Fc[1] * pc[1]   + Fc[2] * pc[2];
        dot += Fc[66] * pc[3]  + Fc[67] * pc[4]  + Fc[68] * pc[5];
        dot += Fc[132] * pc[6] + Fc[133] * pc[7] + Fc[134] * pc[8];
    }
    atomicAdd(&sf[((size_t)b * 64 + slot) * 4096 + P], dot);
}

// ---- D2: interior 5x5 conv — 992 blocks x 4 waves = 3968 wave-tasks (row, 2-ch, b) ----
__global__ __launch_bounds__(256) void k_conv(const float* __restrict__ fsub,
                                              const int* __restrict__ cnt,
                                              const float* __restrict__ K5,
                                              float* __restrict__ sf) {
    int nact = min(*cnt, MAX_SLOTS);
    if (nact == 0) return;
    int wid = blockIdx.x * 4 + (threadIdx.x >> 6);   // 0..3967
    int j = threadIdx.x & 63;
    int r    = 1 + (wid % 62);           // interior rows 1..62
    int rest = wid / 62;                 // 0..63
    int c0   = (rest & 31) * 2;          // channel pair
    int b    = rest >> 5;
    int jc = min(max(j, 1), 62);
    const float* F = fsub + (size_t)b * 278784;
    int base = (r - 1) * 66 + (jc - 1);  // data (r-2, jc-2)
    bool active = (j >= 1 && j <= 62);
    int P = (r << 6) + j;
    for (int s0 = 0; s0 < nact; s0 += 16) {
        float acc[16];
        #pragma unroll
        for (int s = 0; s < 16; ++s) acc[s] = 0.f;
        #pragma unroll
        for (int cc = 0; cc < 2; ++cc) {
            int c = c0 + cc;
            const float* Fc = F + c * 4356 + base;
            float win[25];
            #pragma unroll
            for (int dy = 0; dy < 5; ++dy)
                #pragma unroll
                for (int dx = 0; dx < 5; ++dx)
                    win[dy * 5 + dx] = Fc[dy * 66 + dx];
            const float* kc = K5 + (((size_t)b * 64 + c) * 64 + s0) * 28;  // 16B-aligned rows
            #pragma unroll
            for (int s = 0; s < 16; ++s) {
                #pragma unroll
                for (int k = 0; k < 25; ++k)
                    acc[s] += kc[s * 28 + k] * win[k];
            }
        }
        if (active) {
            int smax = min(16, nact - s0);
            for (int s = 0; s < smax; ++s)
                atomicAdd(&sf[((size_t)b * 64 + (s0 + s)) * 4096 + P], acc[s]);
        }
    }
}

// ---- D3: inline softmax + aggregation + passthrough (1024 blocks, one task each) ----
__global__ __launch_bounds__(256) void k_tail(const float* __restrict__ in,
                                              const int* __restrict__ mask,
                                              const int* __restrict__ cnt,
                                              const int* __restrict__ list,
                                              const float* __restrict__ sf,
                                              float* __restrict__ out) {
    __shared__ float pat8[MAX_SLOTS * 128];  // [s][cc(8)][16 taps]
    int tid = threadIdx.x;
    int blk = blockIdx.x;                    // 0..1023
    int nact = min(*cnt, MAX_SLOTS);
    int up = blk & 63, cg8 = (blk >> 6) & 7, b = blk >> 9;
    int c0 = cg8 * 8;
    const float* inb0 = in + (size_t)b * 2097152 + (size_t)c0 * 16384;
    for (int t = tid; t < nact * 128; t += 256) {
        int s = t >> 7; int rr = t & 127;
        int cc = rr >> 4; int e = rr & 15; int aa = e >> 2; int bb = e & 3;
        int q = list[s]; int qi = q >> 6, qj = q & 63;
        int row = 2 * qi - 1 + aa, col = 2 * qj - 1 + bb;
        float v = (row >= 0 && row < 128 && col >= 0 && col < 128)
                  ? inb0[(size_t)cc * 16384 + row * 128 + col] : 0.f;
        pat8[t] = v;
    }
    __syncthreads();
    int uu = tid >> 7, v = tid & 127;
    int u = up * 2 + uu;
    float y[8];
    #pragma unroll
    for (int cc = 0; cc < 8; ++cc) y[cc] = 0.f;
    if (mask[(u >> 1) * 64 + (v >> 1)] != 0 && nact > 0) {
        int pa = (u + 1) & 1, pb = (v + 1) & 1;
        int i0 = (u + 1 - pa) >> 1, j0 = (v + 1 - pb) >> 1;
        int Pp[4]; int tap[4]; bool val[4];
        #pragma unroll
        for (int di = 0; di < 2; ++di)
            #pragma unroll
            for (int dj = 0; dj < 2; ++dj) {
                int p = di * 2 + dj;
                int i = i0 - di, j = j0 - dj;
                val[p] = (i >= 0 && i < 64 && j >= 0 && j < 64);
                Pp[p] = val[p] ? ((i << 6) + j) : 0;
                tap[p] = (pa + 2 * di) * 4 + (pb + 2 * dj);
            }
        const float* sfb = sf + (size_t)b * 64 * 4096;
        float Mx[4] = {0.f, 0.f, 0.f, 0.f};     // masked rows contribute logit 0
        for (int s = 0; s < nact; ++s) {
            const float* srow = sfb + (size_t)s * 4096;
            #pragma unroll
            for (int p = 0; p < 4; ++p)
                if (val[p]) Mx[p] = fmaxf(Mx[p], 10.f * srow[Pp[p]]);
        }
        float den[4];
        #pragma unroll
        for (int p = 0; p < 4; ++p) den[p] = (float)(L - nact) * expf(-Mx[p]);
        for (int s = 0; s < nact; ++s) {
            const float* srow = sfb + (size_t)s * 4096;
            #pragma unroll
            for (int p = 0; p < 4; ++p)
                if (val[p]) den[p] += expf(10.f * srow[Pp[p]] - Mx[p]);
        }
        float inv[4];
        #pragma unroll
        for (int p = 0; p < 4; ++p) inv[p] = val[p] ? 1.f / den[p] : 0.f;
        for (int s = 0; s < nact; ++s) {
            const float* srow = sfb + (size_t)s * 4096;
            const float* ps = pat8 + s * 128;
            #pragma unroll
            for (int p = 0; p < 4; ++p) {
                if (!val[p]) continue;
                float wv = expf(10.f * srow[Pp[p]] - Mx[p]) * inv[p];
                #pragma unroll
                for (int cc = 0; cc < 8; ++cc)
                    y[cc] += wv * ps[cc * 16 + tap[p]];
            }
        }
        #pragma unroll
        for (int cc = 0; cc < 8; ++cc) y[cc] *= 0.25f;
    }
    size_t ob = (size_t)(b * 192) * 16384 + (size_t)u * 128 + v;
    #pragma unroll
    for (int cc = 0; cc < 8; ++cc) {
        int c = c0 + cc;
        float pval = in[(size_t)(b * 128 + c) * 16384 + u * 128 + v];
        out[ob + (size_t)c * 16384] = pval;            // b_full
        out[ob + (size_t)(c + 64) * 16384] = pval;     // f_full
        out[ob + (size_t)(c + 128) * 16384] = y[cc];   // y
    }
}

extern "C" void kernel_launch(void* const* d_in, const int* in_sizes, int n_in,
                              void* d_out, int out_size, void* d_ws, size_t ws_size,
                              hipStream_t stream) {
    const float* in = (const float*)d_in[0];
    const int* mask = (const int*)d_in[1];
    float* out = (float*)d_out;
    char* ws = (char*)d_ws;
    int* cnt    = (int*)(ws + OFF_CNT);
    int* list   = (int*)(ws + OFF_LIST);
    float* fsub = (float*)(ws + OFF_FSUB);
    float* K5   = (float*)(ws + OFF_K5);
    float* sf   = (float*)(ws + OFF_SF);

    k_init<<<2048, 256, 0, stream>>>(in, mask, cnt, list, fsub, sf);
    k_mid<<<1280, 256, 0, stream>>>(cnt, list, fsub, K5, sf);
    k_conv<<<992, 256, 0, stream>>>(fsub, cnt, K5, sf);
    k_tail<<<1024, 256, 0, stream>>>(in, mask, cnt, list, sf, out);
}

// Round 10
// 149.123 us; speedup vs baseline: 3.8645x; 1.2256x over previous
//
#include <hip/hip_runtime.h>
#include <math.h>

#define MAX_SLOTS 64
#define L 4096

// ws layout (bytes)
#define OFF_CNT   0
#define OFF_LIST  64          // 64 ints
#define OFF_FSUB  512         // 2*64*66*66*4 = 2230272 (zero-padded border)
#define OFF_K5    2230784     // 2*64*64*28*4 = 1835008  [b][c][slot][28] (25 used, 16B-aligned rows)
#define OFF_SF    4065792     // 2*64*4096*4 = 2097152   [b][slot][P]

// ---- D0: subsample + pad zero + sf zero + mask->list ----
__global__ __launch_bounds__(256) void k_init(const float* __restrict__ in,
                                              const int* __restrict__ mask,
                                              int* __restrict__ cnt,
                                              int* __restrict__ list,
                                              float* __restrict__ fsub,
                                              float* __restrict__ sf) {
    int idx = blockIdx.x * 256 + threadIdx.x;      // 524288 data cells
    int j = idx & 63;
    int i = (idx >> 6) & 63;
    int c = (idx >> 12) & 63;
    int b = idx >> 18;
    float v = in[(((b * 128 + c) * 128) + 2 * i) * 128 + 2 * j];
    fsub[(size_t)b * 278784 + c * 4356 + (i + 1) * 66 + (j + 1)] = v;
    sf[idx] = 0.f;                                 // sf is exactly 524288 floats
    if (idx < 33280) {                             // 260 pad cells x 128 planes
        int plane = idx / 260;
        int r = idx - plane * 260;
        int pb = plane >> 6, pc = plane & 63;
        int row, col;
        if (r < 66) { row = 0; col = r; }
        else if (r < 132) { row = 65; col = r - 66; }
        else { int rr = r - 132; row = (rr >> 1) + 1; col = (rr & 1) ? 65 : 0; }
        fsub[(size_t)pb * 278784 + pc * 4356 + row * 66 + col] = 0.f;
    }
    if (blockIdx.x == 0) {
        __shared__ int lcnt;
        if (threadIdx.x == 0) lcnt = 0;
        __syncthreads();
        for (int q = threadIdx.x; q < L; q += 256) {
            int qi = q >> 6, qj = q & 63;
            bool allz = true;
            for (int dy = -1; dy <= 1; ++dy)
                for (int dx = -1; dx <= 1; ++dx) {
                    int y = qi + dy, x = qj + dx;
                    if (y >= 0 && y < 64 && x >= 0 && x < 64)
                        allz = allz && (mask[y * 64 + x] == 0);
                }
            if (allz) {
                int p = atomicAdd(&lcnt, 1);
                if (p < MAX_SLOTS) list[p] = q;
            }
        }
        __syncthreads();
        if (threadIdx.x == 0) *cnt = (lcnt < MAX_SLOTS) ? lcnt : MAX_SLOTS;
    }
}

// ---- D1: blocks 0..127 build K5; blocks 128..1279 border pixels (one task each) ----
__global__ __launch_bounds__(256) void k_mid(const int* __restrict__ cnt,
                                             const int* __restrict__ list,
                                             const float* __restrict__ fsub,
                                             float* __restrict__ K5,
                                             float* __restrict__ sf) {
    __shared__ float smem[5184];     // prep patch9 5184 / border 833
    __shared__ int iflags[16];
    int tid = threadIdx.x;
    int blk = blockIdx.x;
    int nact = min(*cnt, MAX_SLOTS);

    if (blk < 128) {
        // ===== prep: collapsed 5x5 kernels K5[b][c][slot][28] =====
        int slot = blk & 63, b = blk >> 6;
        if (slot >= nact) {
            for (int t = tid; t < 1600; t += 256) {
                int c = t / 25, e = t - c * 25;
                K5[(((size_t)b * 64 + c) * 64 + slot) * 28 + e] = 0.f;
            }
            return;
        }
        float* patch9 = smem;                 // 9*576 floats
        if (tid < 9) iflags[tid] = 0;
        __syncthreads();
        int Q = list[slot];
        const float* F = fsub + (size_t)b * 278784;
        int w = tid >> 6, lane = tid & 63;
        for (int combo = w; combo < 9; combo += 4) {
            int d2 = combo / 3 - 1, d1 = combo % 3 - 1;
            int XQ = ((Q & 63) << 6) + (Q >> 6) + d2;
            if (XQ < 0 || XQ >= L) continue;
            int YQ = ((XQ & 63) << 6) + (XQ >> 6);
            int R = YQ + d1;
            if (R < 0 || R >= L) continue;
            if (lane == 0) iflags[combo] = 1;
            int ri = R >> 6, rj = R & 63;
            const float* Fp = F + ri * 66 + rj;
            float vals[9]; float ss = 0.f;
            #pragma unroll
            for (int k = 0; k < 9; ++k) {
                int t = lane + (k << 6);
                int c = t / 9; int tap = t - c * 9;
                int dy = tap / 3, dx = tap - dy * 3;
                float v = Fp[c * 4356 + dy * 66 + dx];   // data (ri+dy-1, rj+dx-1)
                vals[k] = v; ss += v * v;
            }
            for (int o = 32; o > 0; o >>= 1) ss += __shfl_xor(ss, o);
            float inv = 1.f / fmaxf(sqrtf(ss), 1e-8f);
            float* dst = patch9 + combo * 576;
            #pragma unroll
            for (int k = 0; k < 9; ++k) dst[lane + (k << 6)] = vals[k] * inv;
        }
        __syncthreads();
        // K5[c][oy,ox] = sum_{dy,dx} patch9[(oy-dy, ox-dx)][c][dy,dx]
        for (int t = tid; t < 1600; t += 256) {
            int c = t / 25, e = t - c * 25;
            int oy = e / 5 - 2, ox = e - (e / 5) * 5 - 2;
            float s = 0.f;
            for (int dy = -1; dy <= 1; ++dy) {
                int dd2 = oy - dy; if (dd2 < -1 || dd2 > 1) continue;
                for (int dx = -1; dx <= 1; ++dx) {
                    int dd1 = ox - dx; if (dd1 < -1 || dd1 > 1) continue;
                    int combo = (dd2 + 1) * 3 + (dd1 + 1);
                    if (iflags[combo])
                        s += patch9[combo * 576 + c * 9 + (dy + 1) * 3 + (dx + 1)];
                }
            }
            K5[(((size_t)b * 64 + c) * 64 + slot) * 28 + e] = s;
        }
        return;
    }

    // ===== border: exact per-combo scores for the 252 edge pixels =====
    int bt = blk - 128;                       // 0..1151
    int combo = bt % 9; int rest = bt / 9;
    int slot = rest & 63, b = rest >> 6;
    if (slot >= nact) return;
    int d2 = combo / 3 - 1, d1 = combo % 3 - 1;
    int Q = list[slot];
    int XQ = ((Q & 63) << 6) + (Q >> 6) + d2;
    if (XQ < 0 || XQ >= L) return;
    int YQ = ((XQ & 63) << 6) + (XQ >> 6);
    int R = YQ + d1;
    if (R < 0 || R >= L) return;
    int ri = R >> 6, rj = R & 63;
    const float* F = fsub + (size_t)b * 278784;
    float* patch = smem;                      // 576
    float* red = smem + 576;                  // 256
    const float* Fp = F + ri * 66 + rj;
    auto ld = [&](int t) -> float {
        int c = t / 9; int tap = t - c * 9;
        int dy = tap / 3, dx = tap - dy * 3;
        return Fp[c * 4356 + dy * 66 + dx];
    };
    float v0 = ld(tid), v1 = ld(tid + 256), v2 = (tid < 64) ? ld(tid + 512) : 0.f;
    red[tid] = v0 * v0 + v1 * v1 + v2 * v2;
    __syncthreads();
    if (tid < 64) {
        float a = red[tid] + red[tid + 64] + red[tid + 128] + red[tid + 192];
        for (int o = 32; o > 0; o >>= 1) a += __shfl_xor(a, o);
        if (tid == 0) smem[832] = 1.f / fmaxf(sqrtf(a), 1e-8f);
    }
    __syncthreads();
    float inv = smem[832];
    patch[tid] = v0 * inv; patch[tid + 256] = v1 * inv;
    if (tid < 64) patch[tid + 512] = v2 * inv;
    __syncthreads();
    if (tid >= 252) return;
    int i, j;
    if (tid < 64)       { i = 0;  j = tid; }
    else if (tid < 128) { i = 63; j = tid - 64; }
    else if (tid < 190) { i = tid - 127; j = 0; }
    else                { i = tid - 189; j = 63; }
    int P = (i << 6) + j;
    int XP = (j << 6) + i + d2;
    if (XP < 0 || XP >= L) return;
    int YP = ((XP & 63) << 6) + (XP >> 6);
    int Z = YP + d1;
    if (Z < 0 || Z >= L) return;
    int pi = Z >> 6, pj = Z & 63;
    const float* Fz = F + pi * 66 + pj;
    float dot = 0.f;
    #pragma unroll 4
    for (int c = 0; c < 64; ++c) {
        const float* Fc = Fz + c * 4356;
        const float* pc = patch + c * 9;
        dot += Fc[0] * pc[0]   + Fc[1] * pc[1]   + Fc[2] * pc[2];
        dot += Fc[66] * pc[3]  + Fc[67] * pc[4]  + Fc[68] * pc[5];
        dot += Fc[132] * pc[6] + Fc[133] * pc[7] + Fc[134] * pc[8];
    }
    atomicAdd(&sf[((size_t)b * 64 + slot) * 4096 + P], dot);
}

// ---- D2: interior 5x5 conv — scalar (SMEM) K5 reads, 496 blocks x 4 waves ----
__global__ __launch_bounds__(256) void k_conv(const float* __restrict__ fsub,
                                              const int* __restrict__ cnt,
                                              const float* __restrict__ K5,
                                              float* __restrict__ sf) {
    int nact = min(*cnt, MAX_SLOTS);
    if (nact == 0) return;
    // wave-uniform task id, forced into SGPRs so K5 addressing scalarizes (s_load)
    int wid = __builtin_amdgcn_readfirstlane(blockIdx.x * 4 + (threadIdx.x >> 6)); // 0..1983
    int j = threadIdx.x & 63;
    int r   = 1 + (wid % 62);            // interior rows 1..62
    int cg2 = (wid / 62) & 15;           // 16 chunks of 4 channels
    int b   = wid / 992;
    int jc = min(max(j, 1), 62);
    const float* F = fsub + (size_t)b * 278784;
    int base = (r - 1) * 66 + (jc - 1);  // data (r-2, jc-2)
    bool active = (j >= 1 && j <= 62);
    int P = (r << 6) + j;
    for (int s0 = 0; s0 < nact; s0 += 16) {
        float acc[16];
        #pragma unroll
        for (int s = 0; s < 16; ++s) acc[s] = 0.f;
        #pragma unroll
        for (int cc = 0; cc < 4; ++cc) {
            int c = cg2 * 4 + cc;                    // scalar
            const float* Fc = F + c * 4356 + base;
            float win[25];
            #pragma unroll
            for (int dy = 0; dy < 5; ++dy)
                #pragma unroll
                for (int dx = 0; dx < 5; ++dx)
                    win[dy * 5 + dx] = Fc[dy * 66 + dx];
            const float* kc = K5 + (((size_t)b * 64 + c) * 64 + s0) * 28;  // scalar addr
            #pragma unroll
            for (int s = 0; s < 16; ++s) {
                #pragma unroll
                for (int k = 0; k < 25; ++k)
                    acc[s] += kc[s * 28 + k] * win[k];   // s_load operand
            }
        }
        if (active) {
            int smax = min(16, nact - s0);
            for (int s = 0; s < smax; ++s)
                atomicAdd(&sf[((size_t)b * 64 + (s0 + s)) * 4096 + P], acc[s]);
        }
    }
}

// ---- D3: LDS-staged softmax + aggregation + passthrough (1024 blocks) ----
__global__ __launch_bounds__(256) void k_tail(const float* __restrict__ in,
                                              const int* __restrict__ mask,
                                              const int* __restrict__ cnt,
                                              const int* __restrict__ list,
                                              const float* __restrict__ sf,
                                              float* __restrict__ out) {
    __shared__ float sw[MAX_SLOTS * 192];    // staged sf rows up-1..up+1 -> softmax weights (48 KB)
    __shared__ float pat8[MAX_SLOTS * 128];  // [s][cc(8)][16 taps] (32 KB)
    int tid = threadIdx.x;
    int nact = min(*cnt, MAX_SLOTS);
    int up = blockIdx.x, cg8 = blockIdx.y, b = blockIdx.z;   // u rows 2up, 2up+1
    int c0 = cg8 * 8;
    const float* inb0 = in + (size_t)b * 2097152 + (size_t)c0 * 16384;
    const float* sfb = sf + (size_t)b * 64 * 4096;
    // stage sf rows i = up-1, up, up+1 (zero pad outside)
    for (int t = tid; t < nact * 192; t += 256) {
        int s = t / 192; int rr = t - s * 192;
        int i = up - 1 + (rr >> 6); int jj = rr & 63;
        sw[t] = (i >= 0 && i < 64) ? sfb[(size_t)s * 4096 + (i << 6) + jj] : 0.f;
    }
    for (int t = tid; t < nact * 128; t += 256) {
        int s = t >> 7; int rr = t & 127;
        int cc = rr >> 4; int e = rr & 15; int aa = e >> 2; int bb = e & 3;
        int q = list[s]; int qi = q >> 6, qj = q & 63;
        int row = 2 * qi - 1 + aa, col = 2 * qj - 1 + bb;
        float v = (row >= 0 && row < 128 && col >= 0 && col < 128)
                  ? inb0[(size_t)cc * 16384 + row * 128 + col] : 0.f;
        pat8[t] = v;
    }
    __syncthreads();
    // softmax in LDS: thread t<192 owns staged pixel t; invalid rows -> weight 0
    if (tid < 192 && nact > 0) {
        int i = up - 1 + (tid >> 6);
        if (i >= 0 && i < 64) {
            float M = 0.f;
            for (int s = 0; s < nact; ++s)
                M = fmaxf(M, 10.f * sw[s * 192 + tid]);
            float den = (float)(L - nact) * expf(-M);
            for (int s = 0; s < nact; ++s) {
                float e = expf(10.f * sw[s * 192 + tid] - M);
                sw[s * 192 + tid] = e;
                den += e;
            }
            float inv = 1.f / den;
            for (int s = 0; s < nact; ++s)
                sw[s * 192 + tid] *= inv;
        } else {
            for (int s = 0; s < nact; ++s) sw[s * 192 + tid] = 0.f;
        }
    }
    __syncthreads();
    // aggregation: uu = tid>>7 (u parity), v = tid&127
    int uu = tid >> 7, v = tid & 127;
    int u = up * 2 + uu;
    float y[8];
    #pragma unroll
    for (int cc = 0; cc < 8; ++cc) y[cc] = 0.f;
    if (mask[(u >> 1) * 64 + (v >> 1)] != 0 && nact > 0) {
        int pa = (u + 1) & 1, pb = (v + 1) & 1;
        int i0 = (u + 1 - pa) >> 1, j0 = (v + 1 - pb) >> 1;
        int Wp[4]; int tap[4]; bool val[4];
        #pragma unroll
        for (int di = 0; di < 2; ++di)
            #pragma unroll
            for (int dj = 0; dj < 2; ++dj) {
                int p = di * 2 + dj;
                int i = i0 - di, j = j0 - dj;
                int ii = i - (up - 1);               // 0..2 within staged rows
                val[p] = (j >= 0 && j < 64);         // row validity folded into w=0
                Wp[p] = val[p] ? (ii * 64 + j) : 0;
                tap[p] = (pa + 2 * di) * 4 + (pb + 2 * dj);
            }
        for (int s = 0; s < nact; ++s) {
            const float* wrow = sw + s * 192;
            const float* ps = pat8 + s * 128;
            #pragma unroll
            for (int p = 0; p < 4; ++p) {
                if (!val[p]) continue;
                float wv = wrow[Wp[p]];
                #pragma unroll
                for (int cc = 0; cc < 8; ++cc)
                    y[cc] += wv * ps[cc * 16 + tap[p]];
            }
        }
        #pragma unroll
        for (int cc = 0; cc < 8; ++cc) y[cc] *= 0.25f;
    }
    size_t ob = (size_t)(b * 192) * 16384 + (size_t)u * 128 + v;
    #pragma unroll
    for (int cc = 0; cc < 8; ++cc) {
        int c = c0 + cc;
        float pval = in[(size_t)(b * 128 + c) * 16384 + u * 128 + v];
        out[ob + (size_t)c * 16384] = pval;            // b_full
        out[ob + (size_t)(c + 64) * 16384] = pval;     // f_full
        out[ob + (size_t)(c + 128) * 16384] = y[cc];   // y
    }
}

extern "C" void kernel_launch(void* const* d_in, const int* in_sizes, int n_in,
                              void* d_out, int out_size, void* d_ws, size_t ws_size,
                              hipStream_t stream) {
    const float* in = (const float*)d_in[0];
    const int* mask = (const int*)d_in[1];
    float* out = (float*)d_out;
    char* ws = (char*)d_ws;
    int* cnt    = (int*)(ws + OFF_CNT);
    int* list   = (int*)(ws + OFF_LIST);
    float* fsub = (float*)(ws + OFF_FSUB);
    float* K5   = (float*)(ws + OFF_K5);
    float* sf   = (float*)(ws + OFF_SF);

    k_init<<<2048, 256, 0, stream>>>(in, mask, cnt, list, fsub, sf);
    k_mid<<<1280, 256, 0, stream>>>(cnt, list, fsub, K5, sf);
    k_conv<<<496, 256, 0, stream>>>(fsub, cnt, K5, sf);
    k_tail<<<dim3(64, 8, 2), 256, 0, stream>>>(in, mask, cnt, list, sf, out);
}